// Round 2
// baseline (135.242 us; speedup 1.0000x reference)
//
#include <hip/hip_runtime.h>
#include <hip/hip_bf16.h>

// Problem constants
#define BATCH  16384
#define INF    256
#define GATES  1023
#define NPAD   1024
#define OUTF   128
#define LEAVES 1024

typedef unsigned short ushortT;
typedef short bf16x8 __attribute__((ext_vector_type(8)));
typedef float f32x4 __attribute__((ext_vector_type(4)));

__device__ inline float bf2f(ushortT u) {
    union { unsigned int i; float f; } v;
    v.i = ((unsigned int)u) << 16;
    return v.f;
}
__device__ inline ushortT f2bf(float f) {
    union { float f; unsigned int i; } v;
    v.f = f;
    unsigned int x = v.i;
    unsigned int r = (x + 0x7FFFu + ((x >> 16) & 1u)) >> 16;  // RNE
    return (ushortT)r;
}

// async global->LDS, 16B per lane; ldsptr must be wave-uniform base,
// HW writes base + lane*16 (guide §5 caveat).
__device__ inline void gl2lds16(const void* gptr, void* ldsptr) {
    __builtin_amdgcn_global_load_lds(
        (const __attribute__((address_space(1))) void*)gptr,
        (__attribute__((address_space(3))) void*)ldsptr, 16, 0, 0);
}

// ---------------- fused prep: convert x, convert z, transpose gw, pad gb -------------
// blocks [0,2048): x f32->bf16 (8 elems/thread)
// blocks [2048,2112): z f32->bf16
// blocks [2112,3136): gw transpose->bf16 + gb pad
__global__ void k_prep_all(const float* __restrict__ x, const float* __restrict__ z,
                           const float* __restrict__ gw, const float* __restrict__ gb,
                           ushortT* __restrict__ xh, ushortT* __restrict__ zh,
                           ushortT* __restrict__ gwT, float* __restrict__ gbp) {
    const int b = blockIdx.x, tid = threadIdx.x;
    if (b < 2048) {
        int i = b * 256 + tid;  // 524288 groups of 8
        const float4* p = (const float4*)x + (size_t)i * 2;
        float4 a = p[0], c = p[1];
        ushortT o[8] = {f2bf(a.x), f2bf(a.y), f2bf(a.z), f2bf(a.w),
                        f2bf(c.x), f2bf(c.y), f2bf(c.z), f2bf(c.w)};
        *(bf16x8*)(xh + (size_t)i * 8) = *(bf16x8*)o;
    } else if (b < 2112) {
        int i = (b - 2048) * 256 + tid;  // 16384 groups of 8
        const float4* p = (const float4*)z + (size_t)i * 2;
        float4 a = p[0], c = p[1];
        ushortT o[8] = {f2bf(a.x), f2bf(a.y), f2bf(a.z), f2bf(a.w),
                        f2bf(c.x), f2bf(c.y), f2bf(c.z), f2bf(c.w)};
        *(bf16x8*)(zh + (size_t)i * 8) = *(bf16x8*)o;
    } else {
        int id = (b - 2112) * 256 + tid;  // 262144 threads
        int n = id >> 8, k = id & 255;
        float v = (n < GATES) ? gw[k * GATES + n] : 0.f;
        gwT[n * 256 + k] = f2bf(v);
        if (id < NPAD) gbp[id] = (id < GATES) ? gb[id] : 0.f;
    }
}

// ---------------- GEMM1 (m97 structure): C = sigmoid(A[M,K] * B^T[N,K] + bias) -------
// 256 threads = 4 waves in 2x2; wave tile 64x64; 16x16x32 bf16 MFMA.
template <int BM, int BN, int K, int LDA, int LDB, int LDC>
__global__ __launch_bounds__(256) void gemm1_sig(const ushortT* __restrict__ A,
                                                 const ushortT* __restrict__ B,
                                                 const float* __restrict__ bias,
                                                 ushortT* __restrict__ C) {
    constexpr int MT = BM / 32, NT = BN / 32;
    constexpr int RA = BM / 64, RB = BN / 64;
    __shared__ ushortT sA[BM * 32];
    __shared__ ushortT sB[BN * 32];

    const int tid = threadIdx.x;
    const int wave = tid >> 6, lane = tid & 63;
    const int quad = lane >> 4, l15 = lane & 15;
    const int wr = wave >> 1, wc = wave & 1;
    const int m_wave = wr * (BM / 2), n_wave = wc * (BN / 2);
    const int bm = blockIdx.y * BM, bn = blockIdx.x * BN;

    const int r_in = lane >> 2;
    const int c_in = (lane & 3) * 8;

    f32x4 acc[MT][NT] = {};

    const ushortT* Abase = A + (size_t)bm * LDA;
    const ushortT* Bbase = B + (size_t)bn * LDB;

    for (int k0 = 0; k0 < K; k0 += 32) {
#pragma unroll
        for (int r = 0; r < RA; ++r) {
            int e = wave * RA + r;
            gl2lds16(Abase + (size_t)(e * 16 + r_in) * LDA + k0 + c_in, sA + e * 512);
        }
#pragma unroll
        for (int r = 0; r < RB; ++r) {
            int e = wave * RB + r;
            gl2lds16(Bbase + (size_t)(e * 16 + r_in) * LDB + k0 + c_in, sB + e * 512);
        }
        __syncthreads();

        bf16x8 af[MT], bfr[NT];
#pragma unroll
        for (int i = 0; i < MT; ++i)
            af[i] = *(const bf16x8*)(sA + (m_wave + i * 16 + l15) * 32 + quad * 8);
#pragma unroll
        for (int j = 0; j < NT; ++j)
            bfr[j] = *(const bf16x8*)(sB + (n_wave + j * 16 + l15) * 32 + quad * 8);
#pragma unroll
        for (int i = 0; i < MT; ++i)
#pragma unroll
            for (int j = 0; j < NT; ++j)
                acc[i][j] = __builtin_amdgcn_mfma_f32_16x16x32_bf16(af[i], bfr[j],
                                                                    acc[i][j], 0, 0, 0);
        __syncthreads();
    }

    // C/D mapping: col = lane&15, row = quad*4 + reg (m89-verified)
#pragma unroll
    for (int i = 0; i < MT; ++i) {
        int gm = bm + m_wave + i * 16 + quad * 4;
#pragma unroll
        for (int j = 0; j < NT; ++j) {
            int gn = bn + n_wave + j * 16 + l15;
            float bs = bias[gn];
#pragma unroll
            for (int r = 0; r < 4; ++r) {
                float logit = acc[i][j][r] + bs;
                float g = 1.f / (1.f + __expf(-logit));
                C[(size_t)(gm + r) * LDC + gn] = f2bf(g);
            }
        }
    }
}

// ---------------- fused tree + GEMM2 ----------------
// One block = 32 batch rows, full N=128. Grid 512 blocks (2/CU by 64KB LDS).
// Phase 1: each wave computes leaf densities for 8 rows into LDS (bf16,
//          XOR-swizzled 16B chunks: chunk' = chunk ^ (row&7) keeps fragment
//          reads at the m97 2-way bank pattern despite stride-2048B rows).
// Phase 2: barrier-free K-loop; A fragments from LDS, B (z, 256KB, L2-hot)
//          fragments loaded directly from global (16B/lane).
__global__ __launch_bounds__(256) void k_tree_gemm2(const ushortT* __restrict__ gat,
                                                    const ushortT* __restrict__ zh,
                                                    float* __restrict__ out) {
    __shared__ ushortT sA[32 * 1024];  // 64 KB
    const int tid = threadIdx.x;
    const int wave = tid >> 6, lane = tid & 63;
    const int quad = lane >> 4, l15 = lane & 15;
    const int bm = blockIdx.x * 32;

    // ---- phase 1: tree for rows wave*8 .. wave*8+7 (cooperative, 1 row/wave-step)
    for (int rr = 0; rr < 8; ++rr) {
        const int row = wave * 8 + rr;  // row&7 == rr
        const ushortT* gr = gat + (size_t)(bm + row) * NPAD;

        float P = 1.f;
#pragma unroll
        for (int d = 0; d < 6; ++d) {
            int idx = (1 << d) - 1 + (lane >> (6 - d));
            float g = bf2f(gr[idx]);
            int bit = (lane >> (5 - d)) & 1;
            P *= bit ? (1.f - g) : g;
        }
        float v[16];
        v[0] = P;
#pragma unroll
        for (int d = 0; d < 4; ++d) {
            const int cnt = 1 << d;
            const int base = (1 << (d + 6)) - 1 + (lane << d);
#pragma unroll
            for (int t = 7; t >= 0; --t) {
                if (t < cnt) {
                    float g = bf2f(gr[base + t]);
                    float pv = v[t];
                    float a = pv * g;
                    v[2 * t] = a;
                    v[2 * t + 1] = pv - a;
                }
            }
        }
        ushortT o[16];
#pragma unroll
        for (int t = 0; t < 16; ++t) o[t] = f2bf(v[t]);
        const int c0 = lane * 2;
        *(bf16x8*)(sA + row * 1024 + ((c0 ^ rr) * 8))       = *(bf16x8*)o;
        *(bf16x8*)(sA + row * 1024 + (((c0 + 1) ^ rr) * 8)) = *(bf16x8*)(o + 8);
    }
    __syncthreads();

    // ---- phase 2: GEMM. Waves 2x2: wr = M-half, wc = N-half. Wave tile 16x64.
    const int wr = wave >> 1, wc = wave & 1;
    const int m_wave = wr * 16;
    const int arow = m_wave + l15;
    const int sw = arow & 7;

    f32x4 acc[4] = {};
    const ushortT* zb = zh + (size_t)(wc * 64) * 1024;

#pragma unroll 4
    for (int k0 = 0; k0 < 1024; k0 += 32) {
        const int c = (k0 >> 3) + quad;
        bf16x8 af = *(const bf16x8*)(sA + arow * 1024 + ((c ^ sw) * 8));
#pragma unroll
        for (int j = 0; j < 4; ++j) {
            bf16x8 bf = *(const bf16x8*)(zb + (size_t)(j * 16 + l15) * 1024 + k0 + quad * 8);
            acc[j] = __builtin_amdgcn_mfma_f32_16x16x32_bf16(af, bf, acc[j], 0, 0, 0);
        }
    }

    // epilogue: C/D row = quad*4 + reg, col = l15
    const int gm = bm + m_wave + quad * 4;
#pragma unroll
    for (int j = 0; j < 4; ++j) {
        int gn = wc * 64 + j * 16 + l15;
#pragma unroll
        for (int r = 0; r < 4; ++r)
            out[(size_t)(gm + r) * OUTF + gn] = acc[j][r];
    }
}

// ---------------- launch ----------------
extern "C" void kernel_launch(void* const* d_in, const int* in_sizes, int n_in,
                              void* d_out, int out_size, void* d_ws, size_t ws_size,
                              hipStream_t stream) {
    const float* x  = (const float*)d_in[0];   // 16384 x 256
    const float* gw = (const float*)d_in[1];   // 256 x 1023
    const float* gb = (const float*)d_in[2];   // 1023
    const float* z  = (const float*)d_in[3];   // 128 x 1024
    float* out = (float*)d_out;                // 16384 x 128

    char* ws = (char*)d_ws;
    ushortT* xh  = (ushortT*)(ws + 0);         //  8,388,608 B
    ushortT* gwT = (ushortT*)(ws + 8388608);   //    524,288 B
    ushortT* zh  = (ushortT*)(ws + 8912896);   //    262,144 B
    float*   gbp = (float*)  (ws + 9175040);   //      4,096 B
    ushortT* gat = (ushortT*)(ws + 9179136);   // 33,554,432 B (total ~42.7 MB)

    k_prep_all<<<3136, 256, 0, stream>>>(x, z, gw, gb, xh, zh, gwT, gbp);

    // GEMM1: gatings = sigmoid(x @ gw + gb), M=16384 N=1024 K=256
    gemm1_sig<128, 128, 256, 256, 256, 1024>
        <<<dim3(8, 128), 256, 0, stream>>>(xh, gwT, gbp, gat);

    // fused tree + GEMM2: out = leaf(gat) @ z^T
    k_tree_gemm2<<<512, 256, 0, stream>>>(gat, zh, out);
}

// Round 3
// 116.436 us; speedup vs baseline: 1.1615x; 1.1615x over previous
//
#include <hip/hip_runtime.h>
#include <hip/hip_bf16.h>

// Problem constants
#define BATCH  16384
#define GATES  1023
#define NPAD   1024
#define OUTF   128

typedef unsigned short ushortT;
typedef short bf16x8 __attribute__((ext_vector_type(8)));
typedef float f32x4 __attribute__((ext_vector_type(4)));

__device__ inline float bf2f(ushortT u) {
    union { unsigned int i; float f; } v;
    v.i = ((unsigned int)u) << 16;
    return v.f;
}
__device__ inline ushortT f2bf(float f) {
    union { float f; unsigned int i; } v;
    v.f = f;
    unsigned int x = v.i;
    unsigned int r = (x + 0x7FFFu + ((x >> 16) & 1u)) >> 16;  // RNE
    return (ushortT)r;
}

// async global->LDS, 16B/lane; lds base wave-uniform, HW writes base + lane*16.
__device__ inline void gl2lds16(const void* gptr, void* ldsptr) {
    __builtin_amdgcn_global_load_lds(
        (const __attribute__((address_space(1))) void*)gptr,
        (__attribute__((address_space(3))) void*)ldsptr, 16, 0, 0);
}

// ---------------- prep: gwT (transpose+pad), gbp, zh ----------------
// blocks [0,1024): gw (256x1023 f32) -> gwT (1024x256 bf16, row 1023 zero) + gbp
// blocks [1024,1088): z (128x1024 f32) -> zh bf16
__global__ void k_prep(const float* __restrict__ gw, const float* __restrict__ gb,
                       const float* __restrict__ z, ushortT* __restrict__ gwT,
                       float* __restrict__ gbp, ushortT* __restrict__ zh) {
    const int b = blockIdx.x, t = threadIdx.x;
    if (b < 1024) {
        int id = b * 256 + t;
        int n = id >> 8, k = id & 255;
        float v = (n < GATES) ? gw[k * GATES + n] : 0.f;
        gwT[n * 256 + k] = f2bf(v);
        if (id < NPAD) gbp[id] = (id < GATES) ? gb[id] : 0.f;
    } else {
        int i = (b - 1024) * 256 + t;  // 16384 groups of 8 (131072 elems)
        const float4* p = (const float4*)z + (size_t)i * 2;
        float4 a = p[0], c = p[1];
        ushortT o[8] = {f2bf(a.x), f2bf(a.y), f2bf(a.z), f2bf(a.w),
                        f2bf(c.x), f2bf(c.y), f2bf(c.z), f2bf(c.w)};
        *(bf16x8*)(zh + (size_t)i * 8) = *(bf16x8*)o;
    }
}

// ---------------- mega: x -> gatings -> leaves -> out, one block = 32 rows -----------
// LDS: sG 64KB gating/leaf buffer, chunked [c:32][row:32][off:32] (bf16);
//      sS 16KB staging (two 8KB sub-chunks in m97 [row][32] layout).
// 80KB total -> 2 blocks/CU (8 waves/CU co-resident: barrier drain on one block
// overlaps the other block's MFMAs — the R2 failure was 2 waves/SIMD with
// global-latency inner loops; here every inner-loop load is LDS).
__global__ __launch_bounds__(256) void k_mega(const float* __restrict__ x,
                                              const ushortT* __restrict__ gwT,
                                              const float* __restrict__ gbp,
                                              const ushortT* __restrict__ zh,
                                              float* __restrict__ out) {
    __shared__ ushortT sG[32 * 1024];  // 64 KB
    __shared__ ushortT sS[8192];       // 16 KB

    const int tid = threadIdx.x;
    const int wave = tid >> 6, lane = tid & 63;
    const int quad = lane >> 4, l15 = lane & 15;
    const int wr = wave >> 1, wc = wave & 1;   // 2x2 wave grid; wave tile 16x64
    const int bm = blockIdx.x * 32;
    const int lrow = lane >> 2;                // staging: row within 16-row group
    const int lcol = (lane & 3) * 8;           // staging: elem col within 32

    // ---- preload A: x rows (f32) -> bf16 MFMA fragments, af[c] covers k=c*32+quad*8
    bf16x8 af[8];
    {
        const float* xr = x + (size_t)(bm + wr * 16 + l15) * 256;
#pragma unroll
        for (int c = 0; c < 8; ++c) {
            const float4* p = (const float4*)(xr + c * 32 + quad * 8);
            float4 a = p[0], b = p[1];
            ushortT o[8] = {f2bf(a.x), f2bf(a.y), f2bf(a.z), f2bf(a.w),
                            f2bf(b.x), f2bf(b.y), f2bf(b.z), f2bf(b.w)};
            af[c] = *(bf16x8*)o;
        }
    }

    // ---- P1: gatings = sigmoid(x @ gw + gb) for all 1024 cols, 32 rows ----
    for (int n0 = 0; n0 < 1024; n0 += 128) {
        f32x4 acc[4] = {};
        for (int k0 = 0; k0 < 256; k0 += 64) {
            // stage gwT rows [n0,n0+128) x k [k0,k0+64) -> sS (16 issues of 1KB)
#pragma unroll
            for (int r = 0; r < 4; ++r) {
                int q = wave * 4 + r, kc = q >> 3, e = q & 7;
                gl2lds16(gwT + (size_t)(n0 + e * 16 + lrow) * 256 + k0 + kc * 32 + lcol,
                         sS + kc * 4096 + e * 512);
            }
            __syncthreads();
#pragma unroll
            for (int ks = 0; ks < 2; ++ks) {
                bf16x8 a0 = af[(k0 >> 5) + ks];
#pragma unroll
                for (int j = 0; j < 4; ++j) {
                    bf16x8 b0 = *(const bf16x8*)(sS + ks * 4096 +
                                                 (wc * 64 + j * 16 + l15) * 32 + quad * 8);
                    acc[j] = __builtin_amdgcn_mfma_f32_16x16x32_bf16(a0, b0, acc[j], 0, 0, 0);
                }
            }
            __syncthreads();
        }
        // epilogue: sigmoid -> sG chunked layout. C/D: col=l15, row=quad*4+reg.
        const int row0 = wr * 16 + quad * 4;
#pragma unroll
        for (int j = 0; j < 4; ++j) {
            int col = n0 + wc * 64 + j * 16 + l15;
            float bs = gbp[col];
            int cb = (col >> 5) * 1024 + (col & 31);
#pragma unroll
            for (int r = 0; r < 4; ++r) {
                float g = 1.f / (1.f + __expf(-(acc[j][r] + bs)));
                sG[cb + (row0 + r) * 32] = f2bf(g);
            }
        }
    }
    __syncthreads();

    // ---- P2: tree (all gating reads from LDS), leaves written in-place ----
    {
        const int r0 = wave * 8;
        for (int rr = 0; rr < 8; ++rr) {
            const int row = r0 + rr;
            float P = 1.f;
#pragma unroll
            for (int d = 0; d < 6; ++d) {
                int idx = (1 << d) - 1 + (lane >> (6 - d));
                float g = bf2f(sG[(idx >> 5) * 1024 + row * 32 + (idx & 31)]);
                int bit = (lane >> (5 - d)) & 1;
                P *= bit ? (1.f - g) : g;
            }
            float v[16];
            v[0] = P;
#pragma unroll
            for (int d = 0; d < 4; ++d) {
                const int cnt = 1 << d;
                const int base = (1 << (d + 6)) - 1 + (lane << d);
#pragma unroll
                for (int t = 7; t >= 0; --t) {
                    if (t < cnt) {
                        int gi = base + t;
                        float g = bf2f(sG[(gi >> 5) * 1024 + row * 32 + (gi & 31)]);
                        float pv = v[t];
                        float a = pv * g;
                        v[2 * t] = a;
                        v[2 * t + 1] = pv - a;
                    }
                }
            }
            ushortT o[16];
#pragma unroll
            for (int t = 0; t < 16; ++t) o[t] = f2bf(v[t]);
            // leaves lane*16..+15 live in chunk lane>>1, offs (lane&1)*16..+15,
            // row `row` — exactly row `row`'s gating slots => in-place safe.
            int adr = (lane >> 1) * 1024 + row * 32 + (lane & 1) * 16;
            *(bf16x8*)(sG + adr) = *(bf16x8*)o;
            *(bf16x8*)(sG + adr + 8) = *(bf16x8*)(o + 8);
        }
    }
    __syncthreads();

    // ---- P3: out = leaf @ z^T (leaf from sG, z staged 16KB/iter) ----
    f32x4 acc[4] = {};
    for (int k0 = 0; k0 < 1024; k0 += 64) {
#pragma unroll
        for (int r = 0; r < 4; ++r) {
            int q = wave * 4 + r, kc = q >> 3, e = q & 7;
            gl2lds16(zh + (size_t)(e * 16 + lrow) * 1024 + k0 + kc * 32 + lcol,
                     sS + kc * 4096 + e * 512);
        }
        __syncthreads();
#pragma unroll
        for (int ks = 0; ks < 2; ++ks) {
            bf16x8 a0 = *(const bf16x8*)(sG + ((k0 >> 5) + ks) * 1024 +
                                         (wr * 16 + l15) * 32 + quad * 8);
#pragma unroll
            for (int j = 0; j < 4; ++j) {
                bf16x8 b0 = *(const bf16x8*)(sS + ks * 4096 +
                                             (wc * 64 + j * 16 + l15) * 32 + quad * 8);
                acc[j] = __builtin_amdgcn_mfma_f32_16x16x32_bf16(a0, b0, acc[j], 0, 0, 0);
            }
        }
        __syncthreads();
    }
    const int gm = bm + wr * 16 + quad * 4;
#pragma unroll
    for (int j = 0; j < 4; ++j) {
        int gn = wc * 64 + j * 16 + l15;
#pragma unroll
        for (int r = 0; r < 4; ++r)
            out[(size_t)(gm + r) * OUTF + gn] = acc[j][r];
    }
}

// ---------------- launch ----------------
extern "C" void kernel_launch(void* const* d_in, const int* in_sizes, int n_in,
                              void* d_out, int out_size, void* d_ws, size_t ws_size,
                              hipStream_t stream) {
    const float* x  = (const float*)d_in[0];   // 16384 x 256
    const float* gw = (const float*)d_in[1];   // 256 x 1023
    const float* gb = (const float*)d_in[2];   // 1023
    const float* z  = (const float*)d_in[3];   // 128 x 1024
    float* out = (float*)d_out;                // 16384 x 128

    char* ws = (char*)d_ws;
    ushortT* gwT = (ushortT*)(ws + 0);       // 524,288 B
    ushortT* zh  = (ushortT*)(ws + 524288);  // 262,144 B
    float*   gbp = (float*)  (ws + 786432);  //   4,096 B (total < 1 MB)

    k_prep<<<1088, 256, 0, stream>>>(gw, gb, z, gwT, gbp, zh);
    k_mega<<<512, 256, 0, stream>>>(x, gwT, gbp, zh, out);
}